// Round 1
// baseline (262.374 us; speedup 1.0000x reference)
//
#include <hip/hip_runtime.h>

// mIoU over int32 class maps, NUM=21 (values 0..21; class 0 excluded from iou).
// out[0]=mIoU, out[1..21]=iou for classes 1..21 (f32).
//
// R9: hist_joint identical to R8 (joint 22x22 hist, 1 ds_add/elem, per-wave LDS
// replicas, nt loads, wave-contiguous 2KB-chunk dwordx4 reads, depth-2).
// Tail restructured: reduce+finalize fused into ONE kernel. hist block 0 zeroes
// g+ticket (kernel-boundary visibility). Reduce reads partials ROW-wise
// (coalesced, 4MB instead of ~62MB of strided cachelines), accumulates in
// registers (each thread owns <=2 columns), atomicAdds into g (device scope),
// and the LAST block (device-scope ticket) runs finalize in-place.

#define NUMC  21
#define NBINS 22
#define JBINS (NBINS * NBINS)   // 484
#define RSTR  485               // odd replica stride: spreads banks
#define NREP  4                 // one replica per wave (256 threads)
#define GRID  2048
#define TPB   256
#define RBLK  128               // reduce blocks
#define ROWS  (GRID / RBLK)     // 16 partial-rows per reduce block

typedef int iv4 __attribute__((ext_vector_type(4)));

#define LDP(J) __builtin_nontemporal_load(yp4 + (J))
#define LDT(J) __builtin_nontemporal_load(yt4 + (J))
#define DS4(P, T)                                      \
    atomicAdd(&hh[(T).x * NBINS + (P).x], 1u);         \
    atomicAdd(&hh[(T).y * NBINS + (P).y], 1u);         \
    atomicAdd(&hh[(T).z * NBINS + (P).z], 1u);         \
    atomicAdd(&hh[(T).w * NBINS + (P).w], 1u);

__global__ void __launch_bounds__(256) hist_joint(
        const int* __restrict__ yp, const int* __restrict__ yt,
        unsigned int* __restrict__ partials,
        unsigned int* __restrict__ gz,   // g[484] + ticket, zeroed by block 0
        int n) {
    // zero g + ticket for the fused tail kernel (stream-ordered visibility)
    if (blockIdx.x == 0) {
        for (int i = threadIdx.x; i < JBINS + 8; i += TPB) gz[i] = 0u;
    }

    __shared__ unsigned int h[NREP * RSTR];
    for (int i = threadIdx.x; i < NREP * RSTR; i += TPB) h[i] = 0u;
    __syncthreads();

    const int lane = threadIdx.x & 63;
    const int wave = threadIdx.x >> 6;
    unsigned int* hh = h + wave * RSTR;  // replica per wave

    const iv4* __restrict__ yp4 = (const iv4*)yp;
    const iv4* __restrict__ yt4 = (const iv4*)yt;
    const int n4 = n >> 2;

    // wave-contiguous blocking: wave w covers int4 [w*128, w*128+128) per sweep
    const int gwave   = blockIdx.x * 4 + wave;      // wave id in grid
    const int nwaves  = GRID * 4;
    const int wstride = nwaves * 128;               // int4 per sweep
    const int sweeps  = n4 / wstride;

    if (sweeps * wstride == n4 && (n & 3) == 0) {
        // fast path (exact fit: 8,388,608 = 8 * 8192 * 128)
        const int j0 = gwave * 128 + lane;
        // prologue: sweep 0 in flight (4 KB/wave)
        iv4 pa = LDP(j0),      pb = LDP(j0 + 64);
        iv4 ta = LDT(j0),      tb = LDT(j0 + 64);
        for (int it = 1; it < sweeps; ++it) {
            const int j = j0 + it * wstride;
            iv4 npa = LDP(j),      npb = LDP(j + 64);   // next sweep (4 KB)
            iv4 nta = LDT(j),      ntb = LDT(j + 64);
            DS4(pa, ta) DS4(pb, tb)                     // consume current
            pa = npa; pb = npb; ta = nta; tb = ntb;
        }
        DS4(pa, ta) DS4(pb, tb)
    } else {
        // generic fallback: per-thread grid-stride, 1-deep rotation
        const int stride = GRID * TPB;
        const int i0 = blockIdx.x * TPB + threadIdx.x;
        if (i0 < n4) {
            iv4 p = LDP(i0), t = LDT(i0);
            for (int j = i0 + stride; j < n4; j += stride) {
                iv4 pn = LDP(j), tn = LDT(j);
                DS4(p, t)
                p = pn; t = tn;
            }
            DS4(p, t)
        }
        if (blockIdx.x == 0 && threadIdx.x == 0) {
            for (int k = n4 << 2; k < n; k++)
                atomicAdd(&hh[yt[k] * NBINS + yp[k]], 1u);
        }
    }
#undef DS4
#undef LDP
#undef LDT

    __syncthreads();
    // sum the 4 replicas, write this block's partial row (coalesced, no atomics)
    for (int c = threadIdx.x; c < JBINS; c += TPB) {
        unsigned int s = h[c] + h[RSTR + c] + h[2 * RSTR + c] + h[3 * RSTR + c];
        partials[(size_t)blockIdx.x * JBINS + c] = s;
    }
}

__global__ void __launch_bounds__(256) reduce_finalize(
        const unsigned int* __restrict__ partials,
        unsigned int* __restrict__ g,
        unsigned int* __restrict__ ticket,
        float* __restrict__ out) {
    const int tid = threadIdx.x;

    // --- coalesced row-wise reduction, register accumulation ---
    // thread owns columns {tid, tid+256}; lanes read contiguous dwords per row.
    unsigned int s0 = 0u, s1 = 0u;
    const unsigned int* base = partials + (size_t)blockIdx.x * ROWS * JBINS;
    #pragma unroll 4
    for (int r = 0; r < ROWS; ++r) {
        const unsigned int* row = base + (size_t)r * JBINS;
        s0 += row[tid];
        if (tid < JBINS - 256) s1 += row[tid + 256];
    }
    atomicAdd(&g[tid], s0);                               // device scope
    if (tid < JBINS - 256) atomicAdd(&g[tid + 256], s1);

    // --- last-block ticket (device scope, cross-XCD safe) ---
    __shared__ unsigned int islast;
    __syncthreads();
    if (tid == 0) {
        __threadfence();  // release: g-adds ordered before ticket bump
        unsigned int old = __hip_atomic_fetch_add(
            ticket, 1u, __ATOMIC_ACQ_REL, __HIP_MEMORY_SCOPE_AGENT);
        islast = (old == RBLK - 1) ? 1u : 0u;
    }
    __syncthreads();
    if (!islast) return;
    __threadfence();      // acquire: see all other blocks' g-adds

    // --- finalize on first wave of the last block ---
    const int lane = tid;
    if (lane >= 64) return;
    float iou = 0.0f, pres = 0.0f;
    if (lane >= 1 && lane <= NUMC) {
        unsigned int ct = 0u, cp = 0u;
        #pragma unroll
        for (int k = 0; k < NBINS; k++) {
            ct += __hip_atomic_load(&g[lane * NBINS + k],
                                    __ATOMIC_RELAXED, __HIP_MEMORY_SCOPE_AGENT);
            cp += __hip_atomic_load(&g[k * NBINS + lane],
                                    __ATOMIC_RELAXED, __HIP_MEMORY_SCOPE_AGENT);
        }
        unsigned int ci = __hip_atomic_load(&g[lane * NBINS + lane],
                                    __ATOMIC_RELAXED, __HIP_MEMORY_SCOPE_AGENT);
        float u = (float)ct + (float)cp - (float)ci;
        iou = ((float)ci + 1e-6f) / (u + 1e-6f);
        pres = (ct > 0u) ? 1.0f : 0.0f;
        out[lane] = iou;  // out[1..21]
    }
    float v = iou * pres, pc = pres;
    #pragma unroll
    for (int off = 32; off > 0; off >>= 1) {
        v += __shfl_down(v, off);
        pc += __shfl_down(pc, off);
    }
    if (lane == 0) out[0] = v / fmaxf(pc, 1.0f);
}

extern "C" void kernel_launch(void* const* d_in, const int* in_sizes, int n_in,
                              void* d_out, int out_size, void* d_ws, size_t ws_size,
                              hipStream_t stream) {
    const int* yp = (const int*)d_in[0];
    const int* yt = (const int*)d_in[1];
    int n = in_sizes[0];
    float* out = (float*)d_out;

    // ws layout: g[484] | ticket+pad[8] | partials[GRID * 484]  (~4.0 MB)
    unsigned int* g = (unsigned int*)d_ws;
    unsigned int* ticket = g + JBINS;
    unsigned int* partials = g + JBINS + 8;

    hist_joint<<<GRID, TPB, 0, stream>>>(yp, yt, partials, g, n);
    reduce_finalize<<<RBLK, TPB, 0, stream>>>(partials, g, ticket, out);
}